// Round 1
// baseline (74.301 us; speedup 1.0000x reference)
//
#include <hip/hip_runtime.h>

#define THREADS 256

// ---------------- forward: split-K partial GEMM ----------------
// P[ks][b][o] = sum_{k in slice ks} A[b,k] * W[o,k]
// grid.x = O/64, grid.y = KS; block = 256
__global__ __launch_bounds__(THREADS) void fwd_partial(
    const float* __restrict__ A, const float* __restrict__ W,
    float* __restrict__ P, int K, int O, int KL) {
  __shared__ float Wt[64][64];   // XOR-swizzled granules
  __shared__ float At[32][64];
  const int tid = threadIdx.x;
  const int obase = blockIdx.x * 64;
  const int ks = blockIdx.y;
  const int kbeg = ks * KL;
  const int kend = kbeg + KL;
  const int to = tid & 31;   // lane o index (o = obase + to + 32*i)
  const int tb = tid >> 5;   // 0..7  (b = tb*4 + j)

  float acc[2][4] = {{0.f,0.f,0.f,0.f},{0.f,0.f,0.f,0.f}};

  for (int k0 = kbeg; k0 < kend; k0 += 64) {
    // stage W tile 64x64 (1024 float4 / 256 threads = 4 each), swizzled
    #pragma unroll
    for (int t = 0; t < 4; ++t) {
      const int id4 = tid + t * THREADS;      // 0..1023
      const int r  = id4 >> 4;                // 0..63
      const int c4 = id4 & 15;                // granule
      const float4 v = *reinterpret_cast<const float4*>(
          &W[(size_t)(obase + r) * K + k0 + (c4 << 2)]);
      *reinterpret_cast<float4*>(&Wt[r][(c4 ^ (r & 15)) << 2]) = v;
    }
    // stage A tile 32x64 (512 float4 / 256 threads = 2 each)
    #pragma unroll
    for (int t = 0; t < 2; ++t) {
      const int id4 = tid + t * THREADS;      // 0..511
      const int r  = id4 >> 4;                // 0..31
      const int c4 = id4 & 15;
      const float4 v = *reinterpret_cast<const float4*>(
          &A[(size_t)r * K + k0 + (c4 << 2)]);
      *reinterpret_cast<float4*>(&At[r][c4 << 2]) = v;
    }
    __syncthreads();

    #pragma unroll
    for (int kk = 0; kk < 64; kk += 4) {
      float4 wv[2], av[4];
      const int g = (((kk >> 2) ^ (to & 15)) << 2);
      wv[0] = *reinterpret_cast<const float4*>(&Wt[to][g]);
      wv[1] = *reinterpret_cast<const float4*>(&Wt[to + 32][g]);
      #pragma unroll
      for (int j = 0; j < 4; ++j)
        av[j] = *reinterpret_cast<const float4*>(&At[(tb << 2) + j][kk]);
      #pragma unroll
      for (int i = 0; i < 2; ++i) {
        #pragma unroll
        for (int j = 0; j < 4; ++j) {
          acc[i][j] = fmaf(wv[i].x, av[j].x, acc[i][j]);
          acc[i][j] = fmaf(wv[i].y, av[j].y, acc[i][j]);
          acc[i][j] = fmaf(wv[i].z, av[j].z, acc[i][j]);
          acc[i][j] = fmaf(wv[i].w, av[j].w, acc[i][j]);
        }
      }
    }
    __syncthreads();
  }

  #pragma unroll
  for (int i = 0; i < 2; ++i) {
    #pragma unroll
    for (int j = 0; j < 4; ++j) {
      const int b = (tb << 2) + j;
      const int o = obase + to + 32 * i;
      P[((size_t)ks * 32 + b) * O + o] = acc[i][j];
    }
  }
}

// ---------------- forward: reduce partials + bias + relu ----------------
__global__ __launch_bounds__(THREADS) void fwd_reduce(
    const float* __restrict__ P, const float* __restrict__ bias,
    float* __restrict__ C, int O, int KS) {
  const int idx = blockIdx.x * THREADS + threadIdx.x;
  const int base = idx << 2;
  if (base >= 32 * O) return;
  const int b = base / O;
  const int o = base - b * O;
  float4 s = make_float4(0.f, 0.f, 0.f, 0.f);
  for (int ks = 0; ks < KS; ++ks) {
    const float4 v = *reinterpret_cast<const float4*>(&P[((size_t)ks * 32 + b) * O + o]);
    s.x += v.x; s.y += v.y; s.z += v.z; s.w += v.w;
  }
  const float4 bv = *reinterpret_cast<const float4*>(&bias[o]);
  float4 r;
  r.x = fmaxf(s.x + bv.x, 0.f);
  r.y = fmaxf(s.y + bv.y, 0.f);
  r.z = fmaxf(s.z + bv.z, 0.f);
  r.w = fmaxf(s.w + bv.w, 0.f);
  *reinterpret_cast<float4*>(&C[base]) = r;
}

// ---------------- fused meta update for all three layers ----------------
// nw[o,i] = mb2 + sum_j mw2[j]*relu(mw1[3j]*vin[i] + mw1[3j+1]*W[o,i] + mw1[3j+2]*vout[o] + mb1[j])
__global__ __launch_bounds__(THREADS) void meta_all(
    const float* __restrict__ w1, const float* __restrict__ w2, const float* __restrict__ w3,
    const float* __restrict__ a0, const float* __restrict__ a1, const float* __restrict__ a2,
    const float* __restrict__ a3,
    float* __restrict__ n1, float* __restrict__ n2, float* __restrict__ n3,
    const float* __restrict__ mw1, const float* __restrict__ mb1,
    const float* __restrict__ mw2, const float* __restrict__ mb2) {
  const int g = blockIdx.x * THREADS + threadIdx.x;     // group of 8 elements
  const int n1c = (2048 * 1024) / 8;                    // 262144
  const int n2c = (2048 * 2048) / 8;                    // 524288

  const float* W; const float* vin; const float* vout; float* nw;
  int sh, e;
  if (g < n1c)            { W = w1; vin = a0; vout = a1; nw = n1; sh = 10; e = g; }
  else if (g < n1c + n2c) { W = w2; vin = a1; vout = a2; nw = n2; sh = 11; e = g - n1c; }
  else                    { W = w3; vin = a2; vout = a3; nw = n3; sh = 11; e = g - n1c - n2c; }

  const int base = e << 3;
  const int o = base >> sh;
  const int i0 = base & ((1 << sh) - 1);

  float w[8], vi[8];
  *reinterpret_cast<float4*>(&w[0])  = *reinterpret_cast<const float4*>(&W[base]);
  *reinterpret_cast<float4*>(&w[4])  = *reinterpret_cast<const float4*>(&W[base + 4]);
  *reinterpret_cast<float4*>(&vi[0]) = *reinterpret_cast<const float4*>(&vin[i0]);
  *reinterpret_cast<float4*>(&vi[4]) = *reinterpret_cast<const float4*>(&vin[i0 + 4]);
  const float vo = vout[o];
  const float c2 = mb2[0];

  float r[32];
  #pragma unroll
  for (int j = 0; j < 32; ++j)
    r[j] = fmaf(mw1[3 * j + 2], vo, mb1[j]);

  float acc[8];
  #pragma unroll
  for (int k = 0; k < 8; ++k) acc[k] = c2;

  #pragma unroll
  for (int j = 0; j < 32; ++j) {
    const float aj = mw1[3 * j];
    const float bj = mw1[3 * j + 1];
    const float mj = mw2[j];
    #pragma unroll
    for (int k = 0; k < 8; ++k) {
      float q = fmaf(aj, vi[k], r[j]);
      float h = fmaf(bj, w[k], q);
      h = fmaxf(h, 0.f);
      acc[k] = fmaf(mj, h, acc[k]);
    }
  }

  float4 o0 = make_float4(acc[0], acc[1], acc[2], acc[3]);
  float4 o1 = make_float4(acc[4], acc[5], acc[6], acc[7]);
  *reinterpret_cast<float4*>(&nw[base])     = o0;
  *reinterpret_cast<float4*>(&nw[base + 4]) = o1;
}

extern "C" void kernel_launch(void* const* d_in, const int* in_sizes, int n_in,
                              void* d_out, int out_size, void* d_ws, size_t ws_size,
                              hipStream_t stream) {
  const float* x   = (const float*)d_in[0];
  const float* w1  = (const float*)d_in[1];
  const float* b1  = (const float*)d_in[2];
  const float* w2  = (const float*)d_in[3];
  const float* b2  = (const float*)d_in[4];
  const float* w3  = (const float*)d_in[5];
  const float* b3  = (const float*)d_in[6];
  const float* mw1 = (const float*)d_in[7];
  const float* mb1 = (const float*)d_in[8];
  const float* mw2 = (const float*)d_in[9];
  const float* mb2 = (const float*)d_in[10];

  float* out = (float*)d_out;                 // [32][1024]
  float* n1  = out + 32 * 1024;               // [2048][1024]
  float* n2  = n1 + 2048 * 1024;              // [2048][2048]
  float* n3  = n2 + 2048 * 2048;              // [1024][2048]

  float* ws   = (float*)d_ws;
  float* a1   = ws;                           // 32*2048
  float* a2   = ws + 65536;                   // 32*2048
  float* part = ws + 131072;                  // up to 16*32*2048? (max 8*32*2048 / 16*32*1024 = 524288 f)

  // L1: K=1024, O=2048, KS=8, KL=128
  fwd_partial<<<dim3(2048 / 64, 8), THREADS, 0, stream>>>(x, w1, part, 1024, 2048, 128);
  fwd_reduce<<<(32 * 2048 / 4) / THREADS, THREADS, 0, stream>>>(part, b1, a1, 2048, 8);
  // L2: K=2048, O=2048, KS=8, KL=256
  fwd_partial<<<dim3(2048 / 64, 8), THREADS, 0, stream>>>(a1, w2, part, 2048, 2048, 256);
  fwd_reduce<<<(32 * 2048 / 4) / THREADS, THREADS, 0, stream>>>(part, b2, a2, 2048, 8);
  // L3: K=2048, O=1024, KS=16, KL=128
  fwd_partial<<<dim3(1024 / 64, 16), THREADS, 0, stream>>>(a2, w3, part, 2048, 1024, 128);
  fwd_reduce<<<(32 * 1024 / 4) / THREADS, THREADS, 0, stream>>>(part, b3, out, 1024, 16);

  // fused meta update (1,048,576 threads -> 4096 blocks)
  meta_all<<<4096, THREADS, 0, stream>>>(w1, w2, w3, x, a1, a2, out,
                                         n1, n2, n3, mw1, mb1, mw2, mb2);
}

// Round 2
// 60.768 us; speedup vs baseline: 1.2227x; 1.2227x over previous
//
#include <hip/hip_runtime.h>

#define THREADS 256

typedef float f2 __attribute__((ext_vector_type(2)));

// ---------------- forward: split-K partial GEMM ----------------
// P[ks][b][o] = sum_{k in slice ks} A[b,k] * W[o,k]
// grid.x = O/64, grid.y = KS; block = 256. KL is a multiple of 64.
__global__ __launch_bounds__(THREADS) void fwd_partial(
    const float* __restrict__ A, const float* __restrict__ W,
    float* __restrict__ P, int K, int O, int KL) {
  __shared__ float Wt[64][64];   // XOR-swizzled granules
  __shared__ float At[32][64];
  const int tid = threadIdx.x;
  const int obase = blockIdx.x * 64;
  const int ks = blockIdx.y;
  const int kbeg = ks * KL;
  const int kend = kbeg + KL;
  const int to = tid & 31;   // lane o index (o = obase + to + 32*i)
  const int tb = tid >> 5;   // 0..7  (b = tb*4 + j)

  float acc[2][4] = {{0.f,0.f,0.f,0.f},{0.f,0.f,0.f,0.f}};

  for (int k0 = kbeg; k0 < kend; k0 += 64) {
    // stage W tile 64x64 (1024 float4 / 256 threads = 4 each), swizzled
    #pragma unroll
    for (int t = 0; t < 4; ++t) {
      const int id4 = tid + t * THREADS;      // 0..1023
      const int r  = id4 >> 4;                // 0..63
      const int c4 = id4 & 15;                // granule
      const float4 v = *reinterpret_cast<const float4*>(
          &W[(size_t)(obase + r) * K + k0 + (c4 << 2)]);
      *reinterpret_cast<float4*>(&Wt[r][(c4 ^ (r & 15)) << 2]) = v;
    }
    // stage A tile 32x64 (512 float4 / 256 threads = 2 each)
    #pragma unroll
    for (int t = 0; t < 2; ++t) {
      const int id4 = tid + t * THREADS;      // 0..511
      const int r  = id4 >> 4;                // 0..31
      const int c4 = id4 & 15;
      const float4 v = *reinterpret_cast<const float4*>(
          &A[(size_t)r * K + k0 + (c4 << 2)]);
      *reinterpret_cast<float4*>(&At[r][c4 << 2]) = v;
    }
    __syncthreads();

    #pragma unroll
    for (int kk = 0; kk < 64; kk += 4) {
      float4 wv[2], av[4];
      const int g = (((kk >> 2) ^ (to & 15)) << 2);
      wv[0] = *reinterpret_cast<const float4*>(&Wt[to][g]);
      wv[1] = *reinterpret_cast<const float4*>(&Wt[to + 32][g]);
      #pragma unroll
      for (int j = 0; j < 4; ++j)
        av[j] = *reinterpret_cast<const float4*>(&At[(tb << 2) + j][kk]);
      #pragma unroll
      for (int i = 0; i < 2; ++i) {
        #pragma unroll
        for (int j = 0; j < 4; ++j) {
          acc[i][j] = fmaf(wv[i].x, av[j].x, acc[i][j]);
          acc[i][j] = fmaf(wv[i].y, av[j].y, acc[i][j]);
          acc[i][j] = fmaf(wv[i].z, av[j].z, acc[i][j]);
          acc[i][j] = fmaf(wv[i].w, av[j].w, acc[i][j]);
        }
      }
    }
    __syncthreads();
  }

  #pragma unroll
  for (int i = 0; i < 2; ++i) {
    #pragma unroll
    for (int j = 0; j < 4; ++j) {
      const int b = (tb << 2) + j;
      const int o = obase + to + 32 * i;
      P[((size_t)ks * 32 + b) * O + o] = acc[i][j];
    }
  }
}

// ---------------- forward: reduce partials + bias + relu ----------------
// one scalar element per thread; KS fully unrolled -> KS independent loads in flight
template<int KS, int O_SH>
__global__ __launch_bounds__(THREADS) void fwd_reduce_t(
    const float* __restrict__ P, const float* __restrict__ bias,
    float* __restrict__ C) {
  const int idx = blockIdx.x * THREADS + threadIdx.x;   // 0 .. 32*O-1
  const int b = idx >> O_SH;
  const int o = idx & ((1 << O_SH) - 1);
  float s = 0.f;
  #pragma unroll
  for (int ks = 0; ks < KS; ++ks)
    s += P[((size_t)(ks * 32 + b) << O_SH) + o];
  C[idx] = fmaxf(s + bias[o], 0.f);
}

// ---------------- fused meta update for all three layers ----------------
// nw[o,i] = mb2 + sum_j mw2[j]*relu(mw1[3j]*vin[i] + mw1[3j+1]*W[o,i] + mw1[3j+2]*vout[o] + mb1[j])
__global__ __launch_bounds__(THREADS) void meta_all(
    const float* __restrict__ w1, const float* __restrict__ w2, const float* __restrict__ w3,
    const float* __restrict__ a0, const float* __restrict__ a1, const float* __restrict__ a2,
    const float* __restrict__ a3,
    float* __restrict__ n1, float* __restrict__ n2, float* __restrict__ n3,
    const float* __restrict__ mw1, const float* __restrict__ mb1,
    const float* __restrict__ mw2, const float* __restrict__ mb2) {
  const int g = blockIdx.x * THREADS + threadIdx.x;     // group of 8 elements
  const int n1c = (2048 * 1024) / 8;                    // 262144
  const int n2c = (2048 * 2048) / 8;                    // 524288

  const float* W; const float* vin; const float* vout; float* nw;
  int sh, e;
  if (g < n1c)            { W = w1; vin = a0; vout = a1; nw = n1; sh = 10; e = g; }
  else if (g < n1c + n2c) { W = w2; vin = a1; vout = a2; nw = n2; sh = 11; e = g - n1c; }
  else                    { W = w3; vin = a2; vout = a3; nw = n3; sh = 11; e = g - n1c - n2c; }

  const int base = e << 3;
  const int o = base >> sh;
  const int i0 = base & ((1 << sh) - 1);

  f2 wv[4], vv[4];
  {
    float4 t0 = *reinterpret_cast<const float4*>(&W[base]);
    float4 t1 = *reinterpret_cast<const float4*>(&W[base + 4]);
    wv[0] = (f2){t0.x, t0.y}; wv[1] = (f2){t0.z, t0.w};
    wv[2] = (f2){t1.x, t1.y}; wv[3] = (f2){t1.z, t1.w};
    float4 u0 = *reinterpret_cast<const float4*>(&vin[i0]);
    float4 u1 = *reinterpret_cast<const float4*>(&vin[i0 + 4]);
    vv[0] = (f2){u0.x, u0.y}; vv[1] = (f2){u0.z, u0.w};
    vv[2] = (f2){u1.x, u1.y}; vv[3] = (f2){u1.z, u1.w};
  }
  const float vo = vout[o];
  const float c2 = mb2[0];

  float r[32];
  #pragma unroll
  for (int j = 0; j < 32; ++j)
    r[j] = fmaf(mw1[3 * j + 2], vo, mb1[j]);

  f2 acc[4];
  #pragma unroll
  for (int p = 0; p < 4; ++p) acc[p] = (f2){c2, c2};

  const f2 zero = (f2){0.f, 0.f};
  #pragma unroll
  for (int j = 0; j < 32; ++j) {
    const float aj = mw1[3 * j];
    const float bj = mw1[3 * j + 1];
    const float mj = mw2[j];
    const f2 a2v = (f2){aj, aj};
    const f2 b2v = (f2){bj, bj};
    const f2 m2v = (f2){mj, mj};
    const f2 r2v = (f2){r[j], r[j]};
    #pragma unroll
    for (int p = 0; p < 4; ++p) {
#if __has_builtin(__builtin_elementwise_fma) && __has_builtin(__builtin_elementwise_max)
      f2 q = __builtin_elementwise_fma(a2v, vv[p], r2v);
      f2 h = __builtin_elementwise_fma(b2v, wv[p], q);
      h = __builtin_elementwise_max(h, zero);
      acc[p] = __builtin_elementwise_fma(m2v, h, acc[p]);
#else
      f2 h;
      h.x = fmaxf(fmaf(bj, wv[p].x, fmaf(aj, vv[p].x, r[j])), 0.f);
      h.y = fmaxf(fmaf(bj, wv[p].y, fmaf(aj, vv[p].y, r[j])), 0.f);
      acc[p].x = fmaf(mj, h.x, acc[p].x);
      acc[p].y = fmaf(mj, h.y, acc[p].y);
#endif
    }
  }

  float4 o0 = make_float4(acc[0].x, acc[0].y, acc[1].x, acc[1].y);
  float4 o1 = make_float4(acc[2].x, acc[2].y, acc[3].x, acc[3].y);
  *reinterpret_cast<float4*>(&nw[base])     = o0;
  *reinterpret_cast<float4*>(&nw[base + 4]) = o1;
}

extern "C" void kernel_launch(void* const* d_in, const int* in_sizes, int n_in,
                              void* d_out, int out_size, void* d_ws, size_t ws_size,
                              hipStream_t stream) {
  const float* x   = (const float*)d_in[0];
  const float* w1  = (const float*)d_in[1];
  const float* b1  = (const float*)d_in[2];
  const float* w2  = (const float*)d_in[3];
  const float* b2  = (const float*)d_in[4];
  const float* w3  = (const float*)d_in[5];
  const float* b3  = (const float*)d_in[6];
  const float* mw1 = (const float*)d_in[7];
  const float* mb1 = (const float*)d_in[8];
  const float* mw2 = (const float*)d_in[9];
  const float* mb2 = (const float*)d_in[10];

  float* out = (float*)d_out;                 // [32][1024]
  float* n1  = out + 32 * 1024;               // [2048][1024]
  float* n2  = n1 + 2048 * 1024;              // [2048][2048]
  float* n3  = n2 + 2048 * 2048;              // [1024][2048]

  float* ws   = (float*)d_ws;
  float* a1   = ws;                           // 32*2048
  float* a2   = ws + 65536;                   // 32*2048
  float* part = ws + 131072;                  // up to 32*32*2048 floats (8 MB)

  // L1: K=1024, O=2048, KS=16, KL=64 -> 512 blocks
  fwd_partial<<<dim3(2048 / 64, 16), THREADS, 0, stream>>>(x, w1, part, 1024, 2048, 64);
  fwd_reduce_t<16, 11><<<(32 * 2048) / THREADS, THREADS, 0, stream>>>(part, b1, a1);
  // L2: K=2048, O=2048, KS=32, KL=64 -> 1024 blocks
  fwd_partial<<<dim3(2048 / 64, 32), THREADS, 0, stream>>>(a1, w2, part, 2048, 2048, 64);
  fwd_reduce_t<32, 11><<<(32 * 2048) / THREADS, THREADS, 0, stream>>>(part, b2, a2);
  // L3: K=2048, O=1024, KS=32, KL=64 -> 512 blocks
  fwd_partial<<<dim3(1024 / 64, 32), THREADS, 0, stream>>>(a2, w3, part, 2048, 1024, 64);
  fwd_reduce_t<32, 10><<<(32 * 1024) / THREADS, THREADS, 0, stream>>>(part, b3, out);

  // fused meta update (1,048,576 threads -> 4096 blocks)
  meta_all<<<4096, THREADS, 0, stream>>>(w1, w2, w3, x, a1, a2, out,
                                         n1, n2, n3, mw1, mb1, mw2, mb2);
}